// Round 7
// baseline (628.437 us; speedup 1.0000x reference)
//
#include <hip/hip_runtime.h>
#include <hip/hip_bf16.h>
#include <stdint.h>

#define NB 2048
#define NR 10
#define ND 1024
#define NTGT (NB * (NR - 1))   /* 18432 targets */
#define NEMB (NB * NR)         /* 20480 embedding rows */
#define INV_TEMP 20.0f

#define BM 128
#define BN 256
#define BK 32
#define NKT (ND / BK)          /* 32 K-tiles */
#define TM_TILES (NB / BM)     /* 16 */
#define TN_TILES (NTGT / BN)   /* 72 */

typedef __attribute__((ext_vector_type(8))) short short8;
typedef __attribute__((ext_vector_type(4))) float floatx4;

#define BAR()    asm volatile("s_barrier" ::: "memory")
#define LGKM0()  asm volatile("s_waitcnt lgkmcnt(0)" ::: "memory")
#define VMCNT0() asm volatile("s_waitcnt vmcnt(0)" ::: "memory")

__device__ __forceinline__ unsigned short f2bf(float f) {
  __hip_bfloat16 h = __float2bfloat16(f);
  return __builtin_bit_cast(unsigned short, h);
}

__device__ __forceinline__ void async16(const __hip_bfloat16* g, __hip_bfloat16* l) {
  __builtin_amdgcn_global_load_lds(
      (const __attribute__((address_space(1))) unsigned int*)g,
      (__attribute__((address_space(3))) unsigned int*)l,
      16, 0, 0);
}

// ---------------------------------------------------------------------------
// Kernel 1 (fused prep): one block per b. Reads the 10 rows of b ONCE:
// computes 10 norms + 9 anchor-dots, writes normalized bf16 A/T, KL, pos_score.
// ---------------------------------------------------------------------------
__global__ __launch_bounds__(256) void prep_kernel(
    const float* __restrict__ emb, const float* __restrict__ scores,
    __hip_bfloat16* __restrict__ Abf, __hip_bfloat16* __restrict__ Tbf,
    float* __restrict__ pos_score, float* __restrict__ kl_out) {
  int b = blockIdx.x;
  int tid = threadIdx.x;             // float4 index within a row (256*4 = 1024)
  int wid = tid >> 6, lane = tid & 63;
  const float* base = emb + (size_t)b * NR * ND;

  float4 v[NR];
  float ss[NR], dt[NR - 1];
#pragma unroll
  for (int r = 0; r < NR; ++r) {
    v[r] = reinterpret_cast<const float4*>(base + (size_t)r * ND)[tid];
    ss[r] = v[r].x * v[r].x + v[r].y * v[r].y + v[r].z * v[r].z + v[r].w * v[r].w;
  }
#pragma unroll
  for (int t = 0; t < NR - 1; ++t)
    dt[t] = v[0].x * v[t + 1].x + v[0].y * v[t + 1].y + v[0].z * v[t + 1].z +
            v[0].w * v[t + 1].w;

#pragma unroll
  for (int off = 32; off; off >>= 1) {
#pragma unroll
    for (int r = 0; r < NR; ++r) ss[r] += __shfl_xor(ss[r], off, 64);
#pragma unroll
    for (int t = 0; t < NR - 1; ++t) dt[t] += __shfl_xor(dt[t], off, 64);
  }
  __shared__ float red[4][2 * NR - 1];
  if (lane == 0) {
#pragma unroll
    for (int r = 0; r < NR; ++r) red[wid][r] = ss[r];
#pragma unroll
    for (int t = 0; t < NR - 1; ++t) red[wid][NR + t] = dt[t];
  }
  __syncthreads();

  float inv[NR];
#pragma unroll
  for (int r = 0; r < NR; ++r) {
    float s = red[0][r] + red[1][r] + red[2][r] + red[3][r];
    inv[r] = 1.0f / fmaxf(sqrtf(s), 1e-12f);
  }

#pragma unroll
  for (int r = 0; r < NR; ++r) {
    __hip_bfloat16* dst;
    if (r == 0)      dst = Abf + (size_t)b * ND;
    else if (r == 1) dst = Tbf + (size_t)b * ND;
    else             dst = Tbf + (size_t)(NB + b * 8 + (r - 2)) * ND;
    ushort4 o;
    o.x = f2bf(v[r].x * inv[r]);
    o.y = f2bf(v[r].y * inv[r]);
    o.z = f2bf(v[r].z * inv[r]);
    o.w = f2bf(v[r].w * inv[r]);
    reinterpret_cast<ushort4*>(dst)[tid] = o;
  }

  if (tid == 0) {
    float rs[NR - 1];
#pragma unroll
    for (int t = 0; t < NR - 1; ++t) {
      float d = red[0][NR + t] + red[1][NR + t] + red[2][NR + t] + red[3][NR + t];
      rs[t] = d * inv[0] * inv[t + 1];
    }
    float sc[NR - 1], ms = -1e30f;
#pragma unroll
    for (int k = 0; k < NR - 1; ++k) { sc[k] = scores[b * (NR - 1) + k]; ms = fmaxf(ms, sc[k]); }
    float se = 0.f;
#pragma unroll
    for (int k = 0; k < NR - 1; ++k) { sc[k] = expf(sc[k] - ms); se += sc[k]; }
    float mr = -1e30f;
#pragma unroll
    for (int k = 0; k < NR - 1; ++k) mr = fmaxf(mr, rs[k]);
    float sr = 0.f;
#pragma unroll
    for (int k = 0; k < NR - 1; ++k) sr += expf(rs[k] - mr);
    float lz = logf(sr) + mr;
    float kl = 0.f;
#pragma unroll
    for (int k = 0; k < NR - 1; ++k) {
      float ce = sc[k] / se;
      kl += ce * logf(ce) - ce * (rs[k] - lz);
    }
    kl_out[b] = kl / (float)(NR - 1);
    pos_score[b] = rs[0];
  }
}

// ---------------------------------------------------------------------------
// Kernel 2: 128x256x32 dbuf bf16 GEMM + sum-exp epilogue, 3 blocks/CU (TLP).
// 48 KiB LDS. Rows are 64 B in LDS; swizzle chunk ^= (row>>1)&3: consecutive
// 8 rows hit 8 distinct bank-quads per beat -> conflict-free (round-6's
// row&3 collided 2-way per beat -> 9.4M conflicts).
// ---------------------------------------------------------------------------

// Stage A-tile K-slice: 128 rows x 32 cols, 1 load/thread.
__device__ __forceinline__ void stage_A(const __hip_bfloat16* __restrict__ gtile,
                                        __hip_bfloat16* lds, int k0, int tid) {
  int lrow = tid >> 2;                 // 0..127
  int chunk = (tid & 3) ^ ((lrow >> 1) & 3);
  const __hip_bfloat16* src = gtile + (size_t)lrow * ND + k0 + chunk * 8;
  __hip_bfloat16* dst = lds + (tid & ~63) * 8;  // wave-uniform base, lane*16B auto
  async16(src, dst);
}

// Stage B-tile K-slice: 256 rows x 32 cols, 2 loads/thread.
__device__ __forceinline__ void stage_B(const __hip_bfloat16* __restrict__ gtile,
                                        __hip_bfloat16* lds, int k0, int tid) {
#pragma unroll
  for (int r = 0; r < 2; ++r) {
    int slot = r * 512 + tid;          // 0..1023
    int lrow = slot >> 2;              // 0..255
    int chunk = (slot & 3) ^ ((lrow >> 1) & 3);
    const __hip_bfloat16* src = gtile + (size_t)lrow * ND + k0 + chunk * 8;
    __hip_bfloat16* dst = lds + (r * 512 + (tid & ~63)) * 8;
    async16(src, dst);
  }
}

// Swizzled fragment read: logical (row, lq) -> short8. Row stride 64 B.
__device__ __forceinline__ short8 frag(const __hip_bfloat16* lds, int row, int lq) {
  int byte = row * 64 + ((lq * 16) ^ (((row >> 1) & 3) << 4));
  return *reinterpret_cast<const short8*>(reinterpret_cast<const char*>(lds) + byte);
}

__global__ __launch_bounds__(512, 6) void gemm_lse_kernel(
    const __hip_bfloat16* __restrict__ A, const __hip_bfloat16* __restrict__ T,
    float* __restrict__ sumexp) {
  // 48 KiB: [As0 128x32][Bs0 256x32][As1][Bs1]
  __shared__ __hip_bfloat16 smem[2 * (BM + BN) * BK];

  int bid = blockIdx.x;             // 1152 = 8 * 144
  int xcd = bid & 7;
  int j = bid >> 3;                 // 0..143
  int tn = xcd * 9 + (j >> 4);      // 9 B-panels per XCD
  int tm = j & 15;

  int tid = threadIdx.x;
  int wid = tid >> 6, lane = tid & 63;
  int wm = wid >> 2, wn = wid & 3;  // 2 x 4 waves; wave tile 64 x 64
  int lrow = lane & 15, lq = lane >> 4;

  const __hip_bfloat16* Ag = A + (size_t)tm * BM * ND;
  const __hip_bfloat16* Tg = T + (size_t)tn * BN * ND;

  floatx4 acc[4][4] = {};

  __hip_bfloat16* As0 = smem;                          // 4096 elems
  __hip_bfloat16* Bs0 = smem + BM * BK;                // 8192 elems
  __hip_bfloat16* As1 = smem + (BM + BN) * BK;
  __hip_bfloat16* Bs1 = smem + (2 * BM + BN) * BK;

  // Prologue: stage kt0 (3 loads/thread), drain (cold), barrier.
  stage_A(Ag, As0, 0, tid);
  stage_B(Tg, Bs0, 0, tid);
  VMCNT0();
  BAR();

#pragma unroll 2
  for (int s = 0; s < NKT; ++s) {
    const int buf = s & 1;
    const __hip_bfloat16* Asb = buf ? As1 : As0;
    const __hip_bfloat16* Bsb = buf ? Bs1 : Bs0;
    __hip_bfloat16* Asn = buf ? As0 : As1;   // staging target for kt s+1
    __hip_bfloat16* Bsn = buf ? Bs0 : Bs1;
    const int kn = ((s + 1) & (NKT - 1)) * BK;  // wrap: last iter re-stages kt0
                                                // into the dead buffer (harmless)

    short8 aF[4], bF[2];

    // ---- phase 0: stage full kt s+1 (3 loads); read aF + b(n0,n1); MFMA n0,n1
    stage_A(Ag, Asn, kn, tid);
    stage_B(Tg, Bsn, kn, tid);
#pragma unroll
    for (int m = 0; m < 4; ++m)
      aF[m] = frag(Asb, wm * 64 + m * 16 + lrow, lq);
#pragma unroll
    for (int n = 0; n < 2; ++n)
      bF[n] = frag(Bsb, wn * 64 + n * 16 + lrow, lq);
    BAR();
    LGKM0();
    __builtin_amdgcn_s_setprio(1);
#pragma unroll
    for (int m = 0; m < 4; ++m)
#pragma unroll
      for (int n = 0; n < 2; ++n)
        acc[m][n] = __builtin_amdgcn_mfma_f32_16x16x32_bf16(aF[m], bF[n], acc[m][n], 0, 0, 0);
    __builtin_amdgcn_s_setprio(0);
    BAR();

    // ---- phase 1: read b(n2,n3); MFMA n2,n3; drain pinned after MFMA
#pragma unroll
    for (int n = 0; n < 2; ++n)
      bF[n] = frag(Bsb, wn * 64 + (n + 2) * 16 + lrow, lq);
    BAR();
    LGKM0();
    __builtin_amdgcn_s_setprio(1);
#pragma unroll
    for (int m = 0; m < 4; ++m)
#pragma unroll
      for (int n = 0; n < 2; ++n)
        acc[m][n + 2] = __builtin_amdgcn_mfma_f32_16x16x32_bf16(aF[m], bF[n], acc[m][n + 2], 0, 0, 0);
    __builtin_amdgcn_s_setprio(0);
    __builtin_amdgcn_sched_barrier(0);   // keep MFMA above the drain
    VMCNT0();                            // kt s+1 landed; cross-block TLP covers
    BAR();
  }

  VMCNT0();  // drain the wrapped final-iteration stages before LDS goes away

  // Epilogue: per C-row partial sum of exp(sim*20) over this block's 256 cols.
#pragma unroll
  for (int m = 0; m < 4; ++m) {
#pragma unroll
    for (int j2 = 0; j2 < 4; ++j2) {
      float s = __expf(acc[m][0][j2] * INV_TEMP) + __expf(acc[m][1][j2] * INV_TEMP) +
                __expf(acc[m][2][j2] * INV_TEMP) + __expf(acc[m][3][j2] * INV_TEMP);
      s += __shfl_xor(s, 1, 64);
      s += __shfl_xor(s, 2, 64);
      s += __shfl_xor(s, 4, 64);
      s += __shfl_xor(s, 8, 64);
      if (lrow == 0) {
        int grow = tm * BM + wm * 64 + m * 16 + lq * 4 + j2;
        atomicAdd(&sumexp[grow], s);
      }
    }
  }
}

// ---------------------------------------------------------------------------
// Kernel 3: final scalar reduction.
// ---------------------------------------------------------------------------
__global__ __launch_bounds__(256) void finalize_kernel(
    const float* __restrict__ sumexp, const float* __restrict__ pos_score,
    const float* __restrict__ kl, float* __restrict__ out) {
  int tid = threadIdx.x;
  float kls = 0.f, ces = 0.f;
  for (int i = tid; i < NB; i += 256) {
    kls += kl[i];
    ces += logf(sumexp[i]) - pos_score[i] * INV_TEMP;
  }
#pragma unroll
  for (int off = 32; off; off >>= 1) {
    kls += __shfl_xor(kls, off, 64);
    ces += __shfl_xor(ces, off, 64);
  }
  __shared__ float sk[4], se4[4];
  int wid = tid >> 6, lane = tid & 63;
  if (lane == 0) { sk[wid] = kls; se4[wid] = ces; }
  __syncthreads();
  if (tid == 0) {
    float k4 = sk[0] + sk[1] + sk[2] + sk[3];
    float e4 = se4[0] + se4[1] + se4[2] + se4[3];
    out[0] = 0.5f * (k4 / (float)NB) + 1.0f * (e4 / (float)NB);
  }
}

extern "C" void kernel_launch(void* const* d_in, const int* in_sizes, int n_in,
                              void* d_out, int out_size, void* d_ws, size_t ws_size,
                              hipStream_t stream) {
  const float* emb = (const float*)d_in[0];
  const float* scores = (const float*)d_in[1];
  float* out = (float*)d_out;

  char* ws = (char*)d_ws;
  size_t offA = 0;
  size_t offT = offA + (size_t)NB * ND * 2;
  size_t offSum = offT + (size_t)NTGT * ND * 2;
  size_t offPos = offSum + (size_t)NB * 4;
  size_t offKl = offPos + (size_t)NB * 4;

  __hip_bfloat16* Abf = (__hip_bfloat16*)(ws + offA);
  __hip_bfloat16* Tbf = (__hip_bfloat16*)(ws + offT);
  float* sumexp = (float*)(ws + offSum);
  float* pos_score = (float*)(ws + offPos);
  float* kl = (float*)(ws + offKl);

  hipMemsetAsync(sumexp, 0, (size_t)NB * 4, stream);
  prep_kernel<<<NB, 256, 0, stream>>>(emb, scores, Abf, Tbf, pos_score, kl);
  gemm_lse_kernel<<<dim3(8 * TM_TILES * TN_TILES / 8), 512, 0, stream>>>(Abf, Tbf, sumexp);
  finalize_kernel<<<1, 256, 0, stream>>>(sumexp, pos_score, kl, out);
}

// Round 8
// 142.159 us; speedup vs baseline: 4.4207x; 4.4207x over previous
//
#include <hip/hip_runtime.h>
#include <hip/hip_bf16.h>
#include <stdint.h>

#define NB 2048
#define NR 10
#define ND 1024
#define NTGT (NB * (NR - 1))   /* 18432 targets */
#define NEMB (NB * NR)         /* 20480 embedding rows */
#define INV_TEMP 20.0f

#define BM 128
#define BN 256
#define BK 32
#define NKT (ND / BK)          /* 32 K-tiles */
#define TM_TILES (NB / BM)     /* 16 */
#define TN_TILES (NTGT / BN)   /* 72 */

typedef __attribute__((ext_vector_type(8))) short short8;
typedef __attribute__((ext_vector_type(4))) float floatx4;

#define BAR()    asm volatile("s_barrier" ::: "memory")
#define LGKM0()  asm volatile("s_waitcnt lgkmcnt(0)" ::: "memory")
#define VMCNT0() asm volatile("s_waitcnt vmcnt(0)" ::: "memory")

__device__ __forceinline__ unsigned short f2bf(float f) {
  __hip_bfloat16 h = __float2bfloat16(f);
  return __builtin_bit_cast(unsigned short, h);
}

__device__ __forceinline__ void async16(const __hip_bfloat16* g, __hip_bfloat16* l) {
  __builtin_amdgcn_global_load_lds(
      (const __attribute__((address_space(1))) unsigned int*)g,
      (__attribute__((address_space(3))) unsigned int*)l,
      16, 0, 0);
}

// ---------------------------------------------------------------------------
// Kernel 1 (fused prep): one block per b. Reads the 10 rows of b ONCE:
// computes 10 norms + 9 anchor-dots, writes normalized bf16 A/T, KL, pos_score.
// ---------------------------------------------------------------------------
__global__ __launch_bounds__(256) void prep_kernel(
    const float* __restrict__ emb, const float* __restrict__ scores,
    __hip_bfloat16* __restrict__ Abf, __hip_bfloat16* __restrict__ Tbf,
    float* __restrict__ pos_score, float* __restrict__ kl_out) {
  int b = blockIdx.x;
  int tid = threadIdx.x;             // float4 index within a row (256*4 = 1024)
  int wid = tid >> 6, lane = tid & 63;
  const float* base = emb + (size_t)b * NR * ND;

  float4 v[NR];
  float ss[NR], dt[NR - 1];
#pragma unroll
  for (int r = 0; r < NR; ++r) {
    v[r] = reinterpret_cast<const float4*>(base + (size_t)r * ND)[tid];
    ss[r] = v[r].x * v[r].x + v[r].y * v[r].y + v[r].z * v[r].z + v[r].w * v[r].w;
  }
#pragma unroll
  for (int t = 0; t < NR - 1; ++t)
    dt[t] = v[0].x * v[t + 1].x + v[0].y * v[t + 1].y + v[0].z * v[t + 1].z +
            v[0].w * v[t + 1].w;

#pragma unroll
  for (int off = 32; off; off >>= 1) {
#pragma unroll
    for (int r = 0; r < NR; ++r) ss[r] += __shfl_xor(ss[r], off, 64);
#pragma unroll
    for (int t = 0; t < NR - 1; ++t) dt[t] += __shfl_xor(dt[t], off, 64);
  }
  __shared__ float red[4][2 * NR - 1];
  if (lane == 0) {
#pragma unroll
    for (int r = 0; r < NR; ++r) red[wid][r] = ss[r];
#pragma unroll
    for (int t = 0; t < NR - 1; ++t) red[wid][NR + t] = dt[t];
  }
  __syncthreads();

  float inv[NR];
#pragma unroll
  for (int r = 0; r < NR; ++r) {
    float s = red[0][r] + red[1][r] + red[2][r] + red[3][r];
    inv[r] = 1.0f / fmaxf(sqrtf(s), 1e-12f);
  }

#pragma unroll
  for (int r = 0; r < NR; ++r) {
    __hip_bfloat16* dst;
    if (r == 0)      dst = Abf + (size_t)b * ND;
    else if (r == 1) dst = Tbf + (size_t)b * ND;
    else             dst = Tbf + (size_t)(NB + b * 8 + (r - 2)) * ND;
    ushort4 o;
    o.x = f2bf(v[r].x * inv[r]);
    o.y = f2bf(v[r].y * inv[r]);
    o.z = f2bf(v[r].z * inv[r]);
    o.w = f2bf(v[r].w * inv[r]);
    reinterpret_cast<ushort4*>(dst)[tid] = o;
  }

  if (tid == 0) {
    float rs[NR - 1];
#pragma unroll
    for (int t = 0; t < NR - 1; ++t) {
      float d = red[0][NR + t] + red[1][NR + t] + red[2][NR + t] + red[3][NR + t];
      rs[t] = d * inv[0] * inv[t + 1];
    }
    float sc[NR - 1], ms = -1e30f;
#pragma unroll
    for (int k = 0; k < NR - 1; ++k) { sc[k] = scores[b * (NR - 1) + k]; ms = fmaxf(ms, sc[k]); }
    float se = 0.f;
#pragma unroll
    for (int k = 0; k < NR - 1; ++k) { sc[k] = expf(sc[k] - ms); se += sc[k]; }
    float mr = -1e30f;
#pragma unroll
    for (int k = 0; k < NR - 1; ++k) mr = fmaxf(mr, rs[k]);
    float sr = 0.f;
#pragma unroll
    for (int k = 0; k < NR - 1; ++k) sr += expf(rs[k] - mr);
    float lz = logf(sr) + mr;
    float kl = 0.f;
#pragma unroll
    for (int k = 0; k < NR - 1; ++k) {
      float ce = sc[k] / se;
      kl += ce * logf(ce) - ce * (rs[k] - lz);
    }
    kl_out[b] = kl / (float)(NR - 1);
    pos_score[b] = rs[0];
  }
}

// ---------------------------------------------------------------------------
// Kernel 2: 128x256x32 dbuf bf16 GEMM + sum-exp epilogue, 2 blocks/CU.
// __launch_bounds__(512,4): budget 128 regs/thread (60 VGPR + 64 acc) — (512,6)
// spilled acc to scratch (round 7: 1.5 GB scratch writes, 5x regression).
// Swizzle chunk ^= (row>>1)&3: per beat (8 lanes = 8 consecutive rows),
// bank-quad = 4*(row&1)+chunk covers all 8 quads -> conflict-free.
// ---------------------------------------------------------------------------

// Stage A-tile K-slice: 128 rows x 32 cols, 1 load/thread.
__device__ __forceinline__ void stage_A(const __hip_bfloat16* __restrict__ gtile,
                                        __hip_bfloat16* lds, int k0, int tid) {
  int lrow = tid >> 2;                 // 0..127
  int chunk = (tid & 3) ^ ((lrow >> 1) & 3);
  const __hip_bfloat16* src = gtile + (size_t)lrow * ND + k0 + chunk * 8;
  __hip_bfloat16* dst = lds + (tid & ~63) * 8;  // wave-uniform base, lane*16B auto
  async16(src, dst);
}

// Stage B-tile K-slice: 256 rows x 32 cols, 2 loads/thread.
__device__ __forceinline__ void stage_B(const __hip_bfloat16* __restrict__ gtile,
                                        __hip_bfloat16* lds, int k0, int tid) {
#pragma unroll
  for (int r = 0; r < 2; ++r) {
    int slot = r * 512 + tid;          // 0..1023
    int lrow = slot >> 2;              // 0..255
    int chunk = (slot & 3) ^ ((lrow >> 1) & 3);
    const __hip_bfloat16* src = gtile + (size_t)lrow * ND + k0 + chunk * 8;
    __hip_bfloat16* dst = lds + (r * 512 + (tid & ~63)) * 8;
    async16(src, dst);
  }
}

// Swizzled fragment read: logical (row, lq) -> short8. Row stride 64 B.
__device__ __forceinline__ short8 frag(const __hip_bfloat16* lds, int row, int lq) {
  int byte = row * 64 + ((lq * 16) ^ (((row >> 1) & 3) << 4));
  return *reinterpret_cast<const short8*>(reinterpret_cast<const char*>(lds) + byte);
}

__global__ __launch_bounds__(512, 4) void gemm_lse_kernel(
    const __hip_bfloat16* __restrict__ A, const __hip_bfloat16* __restrict__ T,
    float* __restrict__ sumexp) {
  // 48 KiB: [As0 128x32][Bs0 256x32][As1][Bs1]
  __shared__ __hip_bfloat16 smem[2 * (BM + BN) * BK];

  int bid = blockIdx.x;             // 1152 = 8 * 144
  int xcd = bid & 7;
  int j = bid >> 3;                 // 0..143
  int tn = xcd * 9 + (j >> 4);      // 9 B-panels per XCD
  int tm = j & 15;

  int tid = threadIdx.x;
  int wid = tid >> 6, lane = tid & 63;
  int wm = wid >> 2, wn = wid & 3;  // 2 x 4 waves; wave tile 64 x 64
  int lrow = lane & 15, lq = lane >> 4;

  const __hip_bfloat16* Ag = A + (size_t)tm * BM * ND;
  const __hip_bfloat16* Tg = T + (size_t)tn * BN * ND;

  floatx4 acc[4][4] = {};

  __hip_bfloat16* As0 = smem;                          // 4096 elems
  __hip_bfloat16* Bs0 = smem + BM * BK;                // 8192 elems
  __hip_bfloat16* As1 = smem + (BM + BN) * BK;
  __hip_bfloat16* Bs1 = smem + (2 * BM + BN) * BK;

  // Prologue: stage kt0 (3 loads/thread), drain (cold), barrier.
  stage_A(Ag, As0, 0, tid);
  stage_B(Tg, Bs0, 0, tid);
  VMCNT0();
  BAR();

#pragma unroll 2
  for (int s = 0; s < NKT; ++s) {
    const int buf = s & 1;
    const __hip_bfloat16* Asb = buf ? As1 : As0;
    const __hip_bfloat16* Bsb = buf ? Bs1 : Bs0;
    __hip_bfloat16* Asn = buf ? As0 : As1;   // staging target for kt s+1
    __hip_bfloat16* Bsn = buf ? Bs0 : Bs1;
    const int kn = ((s + 1) & (NKT - 1)) * BK;  // wrap: last iter re-stages kt0
                                                // into the dead buffer (harmless)

    short8 aF[4], bF[2];

    // ---- phase 0: stage full kt s+1 (3 loads); read aF + b(n0,n1); MFMA n0,n1
    stage_A(Ag, Asn, kn, tid);
    stage_B(Tg, Bsn, kn, tid);
#pragma unroll
    for (int m = 0; m < 4; ++m)
      aF[m] = frag(Asb, wm * 64 + m * 16 + lrow, lq);
#pragma unroll
    for (int n = 0; n < 2; ++n)
      bF[n] = frag(Bsb, wn * 64 + n * 16 + lrow, lq);
    BAR();
    LGKM0();
    __builtin_amdgcn_s_setprio(1);
#pragma unroll
    for (int m = 0; m < 4; ++m)
#pragma unroll
      for (int n = 0; n < 2; ++n)
        acc[m][n] = __builtin_amdgcn_mfma_f32_16x16x32_bf16(aF[m], bF[n], acc[m][n], 0, 0, 0);
    __builtin_amdgcn_s_setprio(0);
    BAR();

    // ---- phase 1: read b(n2,n3); MFMA n2,n3; drain pinned after MFMA
#pragma unroll
    for (int n = 0; n < 2; ++n)
      bF[n] = frag(Bsb, wn * 64 + (n + 2) * 16 + lrow, lq);
    BAR();
    LGKM0();
    __builtin_amdgcn_s_setprio(1);
#pragma unroll
    for (int m = 0; m < 4; ++m)
#pragma unroll
      for (int n = 0; n < 2; ++n)
        acc[m][n + 2] = __builtin_amdgcn_mfma_f32_16x16x32_bf16(aF[m], bF[n], acc[m][n + 2], 0, 0, 0);
    __builtin_amdgcn_s_setprio(0);
    __builtin_amdgcn_sched_barrier(0);   // keep MFMA above the drain
    VMCNT0();                            // kt s+1 landed; cross-block TLP covers
    BAR();
  }

  VMCNT0();  // drain the wrapped final-iteration stages before LDS goes away

  // Epilogue: per C-row partial sum of exp(sim*20) over this block's 256 cols.
#pragma unroll
  for (int m = 0; m < 4; ++m) {
#pragma unroll
    for (int j2 = 0; j2 < 4; ++j2) {
      float s = __expf(acc[m][0][j2] * INV_TEMP) + __expf(acc[m][1][j2] * INV_TEMP) +
                __expf(acc[m][2][j2] * INV_TEMP) + __expf(acc[m][3][j2] * INV_TEMP);
      s += __shfl_xor(s, 1, 64);
      s += __shfl_xor(s, 2, 64);
      s += __shfl_xor(s, 4, 64);
      s += __shfl_xor(s, 8, 64);
      if (lrow == 0) {
        int grow = tm * BM + wm * 64 + m * 16 + lq * 4 + j2;
        atomicAdd(&sumexp[grow], s);
      }
    }
  }
}

// ---------------------------------------------------------------------------
// Kernel 3: final scalar reduction.
// ---------------------------------------------------------------------------
__global__ __launch_bounds__(256) void finalize_kernel(
    const float* __restrict__ sumexp, const float* __restrict__ pos_score,
    const float* __restrict__ kl, float* __restrict__ out) {
  int tid = threadIdx.x;
  float kls = 0.f, ces = 0.f;
  for (int i = tid; i < NB; i += 256) {
    kls += kl[i];
    ces += logf(sumexp[i]) - pos_score[i] * INV_TEMP;
  }
#pragma unroll
  for (int off = 32; off; off >>= 1) {
    kls += __shfl_xor(kls, off, 64);
    ces += __shfl_xor(ces, off, 64);
  }
  __shared__ float sk[4], se4[4];
  int wid = tid >> 6, lane = tid & 63;
  if (lane == 0) { sk[wid] = kls; se4[wid] = ces; }
  __syncthreads();
  if (tid == 0) {
    float k4 = sk[0] + sk[1] + sk[2] + sk[3];
    float e4 = se4[0] + se4[1] + se4[2] + se4[3];
    out[0] = 0.5f * (k4 / (float)NB) + 1.0f * (e4 / (float)NB);
  }
}

extern "C" void kernel_launch(void* const* d_in, const int* in_sizes, int n_in,
                              void* d_out, int out_size, void* d_ws, size_t ws_size,
                              hipStream_t stream) {
  const float* emb = (const float*)d_in[0];
  const float* scores = (const float*)d_in[1];
  float* out = (float*)d_out;

  char* ws = (char*)d_ws;
  size_t offA = 0;
  size_t offT = offA + (size_t)NB * ND * 2;
  size_t offSum = offT + (size_t)NTGT * ND * 2;
  size_t offPos = offSum + (size_t)NB * 4;
  size_t offKl = offPos + (size_t)NB * 4;

  __hip_bfloat16* Abf = (__hip_bfloat16*)(ws + offA);
  __hip_bfloat16* Tbf = (__hip_bfloat16*)(ws + offT);
  float* sumexp = (float*)(ws + offSum);
  float* pos_score = (float*)(ws + offPos);
  float* kl = (float*)(ws + offKl);

  hipMemsetAsync(sumexp, 0, (size_t)NB * 4, stream);
  prep_kernel<<<NB, 256, 0, stream>>>(emb, scores, Abf, Tbf, pos_score, kl);
  gemm_lse_kernel<<<dim3(8 * TM_TILES * TN_TILES / 8), 512, 0, stream>>>(Abf, Tbf, sumexp);
  finalize_kernel<<<1, 256, 0, stream>>>(sumexp, pos_score, kl, out);
}

// Round 9
// 106.335 us; speedup vs baseline: 5.9099x; 1.3369x over previous
//
#include <hip/hip_runtime.h>
#include <hip/hip_bf16.h>
#include <stdint.h>

#define NB 2048
#define NR 10
#define ND 1024
#define NTGT (NB * (NR - 1))   /* 18432 targets */
#define INV_TEMP 20.0f

#define BM 128
#define BN 256
#define BK 64                  /* fp8: 64 B rows in LDS */
#define NKT (ND / BK)          /* 16 K-tiles */
#define TM_TILES (NB / BM)     /* 16 */
#define TN_TILES (NTGT / BN)   /* 72 */

typedef __attribute__((ext_vector_type(4))) float floatx4;

#define BAR()    asm volatile("s_barrier" ::: "memory")
#define LGKM0()  asm volatile("s_waitcnt lgkmcnt(0)" ::: "memory")
#define VMCNT0() asm volatile("s_waitcnt vmcnt(0)" ::: "memory")

__device__ __forceinline__ void async16(const void* g, void* l) {
  __builtin_amdgcn_global_load_lds(
      (const __attribute__((address_space(1))) unsigned int*)g,
      (__attribute__((address_space(3))) unsigned int*)l,
      16, 0, 0);
}

// ---------------------------------------------------------------------------
// Kernel 1 (fused prep): one block per b. Reads the 10 rows of b ONCE:
// computes 10 norms + 9 anchor-dots, writes normalized FP8 (e4m3) A/T rows,
// KL, pos_score. KL/pos_score stay exact fp32.
// ---------------------------------------------------------------------------
__global__ __launch_bounds__(256) void prep_kernel(
    const float* __restrict__ emb, const float* __restrict__ scores,
    unsigned char* __restrict__ A8, unsigned char* __restrict__ T8,
    float* __restrict__ pos_score, float* __restrict__ kl_out) {
  int b = blockIdx.x;
  int tid = threadIdx.x;             // float4 index within a row (256*4 = 1024)
  int wid = tid >> 6, lane = tid & 63;
  const float* base = emb + (size_t)b * NR * ND;

  float4 v[NR];
  float ss[NR], dt[NR - 1];
#pragma unroll
  for (int r = 0; r < NR; ++r) {
    v[r] = reinterpret_cast<const float4*>(base + (size_t)r * ND)[tid];
    ss[r] = v[r].x * v[r].x + v[r].y * v[r].y + v[r].z * v[r].z + v[r].w * v[r].w;
  }
#pragma unroll
  for (int t = 0; t < NR - 1; ++t)
    dt[t] = v[0].x * v[t + 1].x + v[0].y * v[t + 1].y + v[0].z * v[t + 1].z +
            v[0].w * v[t + 1].w;

#pragma unroll
  for (int off = 32; off; off >>= 1) {
#pragma unroll
    for (int r = 0; r < NR; ++r) ss[r] += __shfl_xor(ss[r], off, 64);
#pragma unroll
    for (int t = 0; t < NR - 1; ++t) dt[t] += __shfl_xor(dt[t], off, 64);
  }
  __shared__ float red[4][2 * NR - 1];
  if (lane == 0) {
#pragma unroll
    for (int r = 0; r < NR; ++r) red[wid][r] = ss[r];
#pragma unroll
    for (int t = 0; t < NR - 1; ++t) red[wid][NR + t] = dt[t];
  }
  __syncthreads();

  float inv[NR];
#pragma unroll
  for (int r = 0; r < NR; ++r) {
    float s = red[0][r] + red[1][r] + red[2][r] + red[3][r];
    inv[r] = 1.0f / fmaxf(sqrtf(s), 1e-12f);
  }

  // write normalized fp8 rows (4 bytes/thread/row)
#pragma unroll
  for (int r = 0; r < NR; ++r) {
    unsigned char* dst;
    if (r == 0)      dst = A8 + (size_t)b * ND;
    else if (r == 1) dst = T8 + (size_t)b * ND;
    else             dst = T8 + (size_t)(NB + b * 8 + (r - 2)) * ND;
    int p = 0;
    p = __builtin_amdgcn_cvt_pk_fp8_f32(v[r].x * inv[r], v[r].y * inv[r], p, false);
    p = __builtin_amdgcn_cvt_pk_fp8_f32(v[r].z * inv[r], v[r].w * inv[r], p, true);
    reinterpret_cast<int*>(dst)[tid] = p;
  }

  if (tid == 0) {
    float rs[NR - 1];
#pragma unroll
    for (int t = 0; t < NR - 1; ++t) {
      float d = red[0][NR + t] + red[1][NR + t] + red[2][NR + t] + red[3][NR + t];
      rs[t] = d * inv[0] * inv[t + 1];
    }
    float sc[NR - 1], ms = -1e30f;
#pragma unroll
    for (int k = 0; k < NR - 1; ++k) { sc[k] = scores[b * (NR - 1) + k]; ms = fmaxf(ms, sc[k]); }
    float se = 0.f;
#pragma unroll
    for (int k = 0; k < NR - 1; ++k) { sc[k] = expf(sc[k] - ms); se += sc[k]; }
    float mr = -1e30f;
#pragma unroll
    for (int k = 0; k < NR - 1; ++k) mr = fmaxf(mr, rs[k]);
    float sr = 0.f;
#pragma unroll
    for (int k = 0; k < NR - 1; ++k) sr += expf(rs[k] - mr);
    float lz = logf(sr) + mr;
    float kl = 0.f;
#pragma unroll
    for (int k = 0; k < NR - 1; ++k) {
      float ce = sc[k] / se;
      kl += ce * logf(ce) - ce * (rs[k] - lz);
    }
    kl_out[b] = kl / (float)(NR - 1);
    pos_score[b] = rs[0];
  }
}

// ---------------------------------------------------------------------------
// Kernel 2: 128x256x64 FP8 (e4m3) dbuf GEMM + sum-exp epilogue, 2 blocks/CU.
// Round-6/8 skeleton unchanged; dtype fp8 halves LDS bytes & staging per FLOP,
// BK doubles -> 16 iters (half the sync points). mfma_f32_16x16x32_fp8_fp8
// (i64 operands; frag k-map identical to bf16 16x16x32; C/D layout unchanged).
// Swizzle (64 B rows, 16 B staging granularity): 16B-unit u ^= (row>>1)&3
// -> worst-case 2-way bank aliasing (free, m136).
// ---------------------------------------------------------------------------

// Stage A K-slice: 128 rows x 64 B = 8 KB, 1 load/thread.
__device__ __forceinline__ void stage_A8(const unsigned char* __restrict__ gtile,
                                         unsigned char* lds, int k0, int tid) {
  int lrow = tid >> 2;                 // 0..127
  int u = (tid & 3) ^ ((lrow >> 1) & 3);
  const unsigned char* src = gtile + (size_t)lrow * ND + k0 + u * 16;
  unsigned char* dst = lds + (tid & ~63) * 16;  // wave-uniform base, +lane*16B
  async16(src, dst);
}

// Stage B K-slice: 256 rows x 64 B = 16 KB, 2 loads/thread.
__device__ __forceinline__ void stage_B8(const unsigned char* __restrict__ gtile,
                                         unsigned char* lds, int k0, int tid) {
#pragma unroll
  for (int r = 0; r < 2; ++r) {
    int slot = r * 512 + tid;          // 0..1023
    int lrow = slot >> 2;              // 0..255
    int u = (slot & 3) ^ ((lrow >> 1) & 3);
    const unsigned char* src = gtile + (size_t)lrow * ND + k0 + u * 16;
    unsigned char* dst = lds + (r * 512 + (tid & ~63)) * 16;
    async16(src, dst);
  }
}

// Swizzled fragment read: logical (row, kstep, lq) -> 8 fp8 as i64.
__device__ __forceinline__ long frag8(const unsigned char* lds, int row, int kstep, int lq) {
  int byte = row * 64 + ((kstep * 32 + lq * 8) ^ (((row >> 1) & 3) << 4));
  return *reinterpret_cast<const long*>(lds + byte);
}

__global__ __launch_bounds__(512, 4) void gemm_lse_kernel(
    const unsigned char* __restrict__ A, const unsigned char* __restrict__ T,
    float* __restrict__ sumexp) {
  // 48 KiB: [As0 8K][Bs0 16K][As1 8K][Bs1 16K]
  __shared__ unsigned char smem[2 * (BM + BN) * BK];

  int bid = blockIdx.x;             // 1152 = 8 * 144
  int xcd = bid & 7;
  int j = bid >> 3;                 // 0..143
  int tn = xcd * 9 + (j >> 4);      // 9 B-panels per XCD
  int tm = j & 15;

  int tid = threadIdx.x;
  int wid = tid >> 6, lane = tid & 63;
  int wm = wid >> 2, wn = wid & 3;  // 2 x 4 waves; wave tile 64 x 64
  int lrow = lane & 15, lq = lane >> 4;

  const unsigned char* Ag = A + (size_t)tm * BM * ND;
  const unsigned char* Tg = T + (size_t)tn * BN * ND;

  floatx4 acc[4][4] = {};

  unsigned char* As0 = smem;                          // 8 KB
  unsigned char* Bs0 = smem + BM * BK;                // 16 KB
  unsigned char* As1 = smem + (BM + BN) * BK;
  unsigned char* Bs1 = smem + (2 * BM + BN) * BK;

  // Prologue: stage kt0 (3 loads/thread), drain (cold), barrier.
  stage_A8(Ag, As0, 0, tid);
  stage_B8(Tg, Bs0, 0, tid);
  VMCNT0();
  BAR();

#pragma unroll 2
  for (int s = 0; s < NKT; ++s) {
    const int buf = s & 1;
    const unsigned char* Asb = buf ? As1 : As0;
    const unsigned char* Bsb = buf ? Bs1 : Bs0;
    unsigned char* Asn = buf ? As0 : As1;    // staging target for kt s+1
    unsigned char* Bsn = buf ? Bs0 : Bs1;
    const int kn = ((s + 1) & (NKT - 1)) * BK;  // wrap: last iter re-stages kt0
                                                // into the dead buffer (harmless)

    long aF[4][2], bF[2][2];

    // ---- phase 0: stage full kt s+1 (3 loads); read aF + b(n0,n1); MFMA n0,n1
    stage_A8(Ag, Asn, kn, tid);
    stage_B8(Tg, Bsn, kn, tid);
#pragma unroll
    for (int m = 0; m < 4; ++m)
#pragma unroll
      for (int kk = 0; kk < 2; ++kk)
        aF[m][kk] = frag8(Asb, wm * 64 + m * 16 + lrow, kk, lq);
#pragma unroll
    for (int n = 0; n < 2; ++n)
#pragma unroll
      for (int kk = 0; kk < 2; ++kk)
        bF[n][kk] = frag8(Bsb, wn * 64 + n * 16 + lrow, kk, lq);
    BAR();
    LGKM0();
    __builtin_amdgcn_s_setprio(1);
#pragma unroll
    for (int kk = 0; kk < 2; ++kk)
#pragma unroll
      for (int m = 0; m < 4; ++m)
#pragma unroll
        for (int n = 0; n < 2; ++n)
          acc[m][n] = __builtin_amdgcn_mfma_f32_16x16x32_fp8_fp8(aF[m][kk], bF[n][kk], acc[m][n], 0, 0, 0);
    __builtin_amdgcn_s_setprio(0);
    BAR();

    // ---- phase 1: read b(n2,n3); MFMA n2,n3; drain pinned after MFMA
#pragma unroll
    for (int n = 0; n < 2; ++n)
#pragma unroll
      for (int kk = 0; kk < 2; ++kk)
        bF[n][kk] = frag8(Bsb, wn * 64 + (n + 2) * 16 + lrow, kk, lq);
    BAR();
    LGKM0();
    __builtin_amdgcn_s_setprio(1);
#pragma unroll
    for (int kk = 0; kk < 2; ++kk)
#pragma unroll
      for (int m = 0; m < 4; ++m)
#pragma unroll
        for (int n = 0; n < 2; ++n)
          acc[m][n + 2] = __builtin_amdgcn_mfma_f32_16x16x32_fp8_fp8(aF[m][kk], bF[n][kk], acc[m][n + 2], 0, 0, 0);
    __builtin_amdgcn_s_setprio(0);
    __builtin_amdgcn_sched_barrier(0);   // keep MFMA above the drain
    VMCNT0();                            // kt s+1 landed; cross-block TLP covers
    BAR();
  }

  VMCNT0();  // drain the wrapped final-iteration stages before LDS goes away

  // Epilogue: per C-row partial sum of exp(sim*20) over this block's 256 cols.
#pragma unroll
  for (int m = 0; m < 4; ++m) {
#pragma unroll
    for (int j2 = 0; j2 < 4; ++j2) {
      float s = __expf(acc[m][0][j2] * INV_TEMP) + __expf(acc[m][1][j2] * INV_TEMP) +
                __expf(acc[m][2][j2] * INV_TEMP) + __expf(acc[m][3][j2] * INV_TEMP);
      s += __shfl_xor(s, 1, 64);
      s += __shfl_xor(s, 2, 64);
      s += __shfl_xor(s, 4, 64);
      s += __shfl_xor(s, 8, 64);
      if (lrow == 0) {
        int grow = tm * BM + wm * 64 + m * 16 + lq * 4 + j2;
        atomicAdd(&sumexp[grow], s);
      }
    }
  }
}

// ---------------------------------------------------------------------------
// Kernel 3: final scalar reduction.
// ---------------------------------------------------------------------------
__global__ __launch_bounds__(256) void finalize_kernel(
    const float* __restrict__ sumexp, const float* __restrict__ pos_score,
    const float* __restrict__ kl, float* __restrict__ out) {
  int tid = threadIdx.x;
  float kls = 0.f, ces = 0.f;
  for (int i = tid; i < NB; i += 256) {
    kls += kl[i];
    ces += logf(sumexp[i]) - pos_score[i] * INV_TEMP;
  }
#pragma unroll
  for (int off = 32; off; off >>= 1) {
    kls += __shfl_xor(kls, off, 64);
    ces += __shfl_xor(ces, off, 64);
  }
  __shared__ float sk[4], se4[4];
  int wid = tid >> 6, lane = tid & 63;
  if (lane == 0) { sk[wid] = kls; se4[wid] = ces; }
  __syncthreads();
  if (tid == 0) {
    float k4 = sk[0] + sk[1] + sk[2] + sk[3];
    float e4 = se4[0] + se4[1] + se4[2] + se4[3];
    out[0] = 0.5f * (k4 / (float)NB) + 1.0f * (e4 / (float)NB);
  }
}

extern "C" void kernel_launch(void* const* d_in, const int* in_sizes, int n_in,
                              void* d_out, int out_size, void* d_ws, size_t ws_size,
                              hipStream_t stream) {
  const float* emb = (const float*)d_in[0];
  const float* scores = (const float*)d_in[1];
  float* out = (float*)d_out;

  char* ws = (char*)d_ws;
  size_t offA = 0;
  size_t offT = offA + (size_t)NB * ND;          // fp8: 1 B/elem
  size_t offSum = offT + (size_t)NTGT * ND;
  size_t offPos = offSum + (size_t)NB * 4;
  size_t offKl = offPos + (size_t)NB * 4;

  unsigned char* A8 = (unsigned char*)(ws + offA);
  unsigned char* T8 = (unsigned char*)(ws + offT);
  float* sumexp = (float*)(ws + offSum);
  float* pos_score = (float*)(ws + offPos);
  float* kl = (float*)(ws + offKl);

  hipMemsetAsync(sumexp, 0, (size_t)NB * 4, stream);
  prep_kernel<<<NB, 256, 0, stream>>>(emb, scores, A8, T8, pos_score, kl);
  gemm_lse_kernel<<<dim3(TM_TILES * TN_TILES), 512, 0, stream>>>(A8, T8, sumexp);
  finalize_kernel<<<1, 256, 0, stream>>>(sumexp, pos_score, kl, out);
}

// Round 10
// 97.944 us; speedup vs baseline: 6.4163x; 1.0857x over previous
//
#include <hip/hip_runtime.h>
#include <hip/hip_bf16.h>
#include <stdint.h>

#define NB 2048
#define NR 10
#define ND 1024
#define NTGT (NB * (NR - 1))   /* 18432 targets */
#define INV_TEMP 20.0f

#define BM 128
#define BN 256
#define BK 64                  /* fp8: 64 B rows in LDS */
#define NKT (ND / BK)          /* 16 K-tiles */
#define TM_TILES (NB / BM)     /* 16 */
#define TN_TILES (NTGT / BN)   /* 72 */

typedef __attribute__((ext_vector_type(4))) float floatx4;
typedef __attribute__((ext_vector_type(2))) long longx2;

#define BAR()    asm volatile("s_barrier" ::: "memory")
#define LGKM0()  asm volatile("s_waitcnt lgkmcnt(0)" ::: "memory")
#define VMCNT0() asm volatile("s_waitcnt vmcnt(0)" ::: "memory")

__device__ __forceinline__ void async16(const void* g, void* l) {
  __builtin_amdgcn_global_load_lds(
      (const __attribute__((address_space(1))) unsigned int*)g,
      (__attribute__((address_space(3))) unsigned int*)l,
      16, 0, 0);
}

// ---------------------------------------------------------------------------
// Kernel 1 (fused prep): one block per b. Reads the 10 rows of b ONCE:
// computes 10 norms + 9 anchor-dots, writes normalized FP8 (e4m3) A/T rows,
// KL, pos_score. KL/pos_score stay exact fp32.
// ---------------------------------------------------------------------------
__global__ __launch_bounds__(256) void prep_kernel(
    const float* __restrict__ emb, const float* __restrict__ scores,
    unsigned char* __restrict__ A8, unsigned char* __restrict__ T8,
    float* __restrict__ pos_score, float* __restrict__ kl_out) {
  int b = blockIdx.x;
  int tid = threadIdx.x;             // float4 index within a row (256*4 = 1024)
  int wid = tid >> 6, lane = tid & 63;
  const float* base = emb + (size_t)b * NR * ND;

  float4 v[NR];
  float ss[NR], dt[NR - 1];
#pragma unroll
  for (int r = 0; r < NR; ++r) {
    v[r] = reinterpret_cast<const float4*>(base + (size_t)r * ND)[tid];
    ss[r] = v[r].x * v[r].x + v[r].y * v[r].y + v[r].z * v[r].z + v[r].w * v[r].w;
  }
#pragma unroll
  for (int t = 0; t < NR - 1; ++t)
    dt[t] = v[0].x * v[t + 1].x + v[0].y * v[t + 1].y + v[0].z * v[t + 1].z +
            v[0].w * v[t + 1].w;

#pragma unroll
  for (int off = 32; off; off >>= 1) {
#pragma unroll
    for (int r = 0; r < NR; ++r) ss[r] += __shfl_xor(ss[r], off, 64);
#pragma unroll
    for (int t = 0; t < NR - 1; ++t) dt[t] += __shfl_xor(dt[t], off, 64);
  }
  __shared__ float red[4][2 * NR - 1];
  if (lane == 0) {
#pragma unroll
    for (int r = 0; r < NR; ++r) red[wid][r] = ss[r];
#pragma unroll
    for (int t = 0; t < NR - 1; ++t) red[wid][NR + t] = dt[t];
  }
  __syncthreads();

  float inv[NR];
#pragma unroll
  for (int r = 0; r < NR; ++r) {
    float s = red[0][r] + red[1][r] + red[2][r] + red[3][r];
    inv[r] = 1.0f / fmaxf(sqrtf(s), 1e-12f);
  }

  // write normalized fp8 rows (4 bytes/thread/row)
#pragma unroll
  for (int r = 0; r < NR; ++r) {
    unsigned char* dst;
    if (r == 0)      dst = A8 + (size_t)b * ND;
    else if (r == 1) dst = T8 + (size_t)b * ND;
    else             dst = T8 + (size_t)(NB + b * 8 + (r - 2)) * ND;
    int p = 0;
    p = __builtin_amdgcn_cvt_pk_fp8_f32(v[r].x * inv[r], v[r].y * inv[r], p, false);
    p = __builtin_amdgcn_cvt_pk_fp8_f32(v[r].z * inv[r], v[r].w * inv[r], p, true);
    reinterpret_cast<int*>(dst)[tid] = p;
  }

  if (tid == 0) {
    float rs[NR - 1];
#pragma unroll
    for (int t = 0; t < NR - 1; ++t) {
      float d = red[0][NR + t] + red[1][NR + t] + red[2][NR + t] + red[3][NR + t];
      rs[t] = d * inv[0] * inv[t + 1];
    }
    float sc[NR - 1], ms = -1e30f;
#pragma unroll
    for (int k = 0; k < NR - 1; ++k) { sc[k] = scores[b * (NR - 1) + k]; ms = fmaxf(ms, sc[k]); }
    float se = 0.f;
#pragma unroll
    for (int k = 0; k < NR - 1; ++k) { sc[k] = expf(sc[k] - ms); se += sc[k]; }
    float mr = -1e30f;
#pragma unroll
    for (int k = 0; k < NR - 1; ++k) mr = fmaxf(mr, rs[k]);
    float sr = 0.f;
#pragma unroll
    for (int k = 0; k < NR - 1; ++k) sr += expf(rs[k] - mr);
    float lz = logf(sr) + mr;
    float kl = 0.f;
#pragma unroll
    for (int k = 0; k < NR - 1; ++k) {
      float ce = sc[k] / se;
      kl += ce * logf(ce) - ce * (rs[k] - lz);
    }
    kl_out[b] = kl / (float)(NR - 1);
    pos_score[b] = rs[0];
  }
}

// ---------------------------------------------------------------------------
// Kernel 2: 128x256x64 FP8 (e4m3) dbuf GEMM + sum-exp epilogue, 2 blocks/CU.
// Fragment reads are ONE ds_read_b128 per fragment-pair at offset lq*16
// (identical to the round-8 bf16 pattern, measured 0 conflicts).
// k-permutation invariance: MFMA call kk uses physical k bytes
// row*64 + lq*16 + kk*8..+7 for BOTH A and B -> dot product unchanged,
// union over (lq,kk) covers all 64 k's exactly once.
// Swizzle at 16B units: u ^= (row>>1)&3 on both staging source and read.
// ---------------------------------------------------------------------------

// Stage A K-slice: 128 rows x 64 B = 8 KB, 1 load/thread.
__device__ __forceinline__ void stage_A8(const unsigned char* __restrict__ gtile,
                                         unsigned char* lds, int k0, int tid) {
  int lrow = tid >> 2;                 // 0..127
  int u = (tid & 3) ^ ((lrow >> 1) & 3);
  const unsigned char* src = gtile + (size_t)lrow * ND + k0 + u * 16;
  unsigned char* dst = lds + (tid & ~63) * 16;  // wave-uniform base, +lane*16B
  async16(src, dst);
}

// Stage B K-slice: 256 rows x 64 B = 16 KB, 2 loads/thread.
__device__ __forceinline__ void stage_B8(const unsigned char* __restrict__ gtile,
                                         unsigned char* lds, int k0, int tid) {
#pragma unroll
  for (int r = 0; r < 2; ++r) {
    int slot = r * 512 + tid;          // 0..1023
    int lrow = slot >> 2;              // 0..255
    int u = (slot & 3) ^ ((lrow >> 1) & 3);
    const unsigned char* src = gtile + (size_t)lrow * ND + k0 + u * 16;
    unsigned char* dst = lds + (r * 512 + (tid & ~63)) * 16;
    async16(src, dst);
  }
}

// Swizzled fragment-pair read: one b128; .x = kk0 (bytes lq*16..+7),
// .y = kk1 (bytes lq*16+8..+15).
__device__ __forceinline__ longx2 frag8(const unsigned char* lds, int row, int lq) {
  int byte = row * 64 + ((lq * 16) ^ (((row >> 1) & 3) << 4));
  return *reinterpret_cast<const longx2*>(lds + byte);
}

__global__ __launch_bounds__(512, 4) void gemm_lse_kernel(
    const unsigned char* __restrict__ A, const unsigned char* __restrict__ T,
    float* __restrict__ sumexp) {
  // 48 KiB: [As0 8K][Bs0 16K][As1 8K][Bs1 16K]
  __shared__ unsigned char smem[2 * (BM + BN) * BK];

  int bid = blockIdx.x;             // 1152 = 8 * 144
  int xcd = bid & 7;
  int j = bid >> 3;                 // 0..143
  int tn = xcd * 9 + (j >> 4);      // 9 B-panels per XCD
  int tm = j & 15;

  int tid = threadIdx.x;
  int wid = tid >> 6, lane = tid & 63;
  int wm = wid >> 2, wn = wid & 3;  // 2 x 4 waves; wave tile 64 x 64
  int lrow = lane & 15, lq = lane >> 4;

  const unsigned char* Ag = A + (size_t)tm * BM * ND;
  const unsigned char* Tg = T + (size_t)tn * BN * ND;

  floatx4 acc[4][4] = {};

  unsigned char* As0 = smem;                          // 8 KB
  unsigned char* Bs0 = smem + BM * BK;                // 16 KB
  unsigned char* As1 = smem + (BM + BN) * BK;
  unsigned char* Bs1 = smem + (2 * BM + BN) * BK;

  // Prologue: stage kt0 (3 loads/thread), drain (cold), barrier.
  stage_A8(Ag, As0, 0, tid);
  stage_B8(Tg, Bs0, 0, tid);
  VMCNT0();
  BAR();

#pragma unroll 2
  for (int s = 0; s < NKT; ++s) {
    const int buf = s & 1;
    const unsigned char* Asb = buf ? As1 : As0;
    const unsigned char* Bsb = buf ? Bs1 : Bs0;
    unsigned char* Asn = buf ? As0 : As1;    // staging target for kt s+1
    unsigned char* Bsn = buf ? Bs0 : Bs1;
    const int kn = ((s + 1) & (NKT - 1)) * BK;  // wrap: last iter re-stages kt0
                                                // into the dead buffer (harmless)

    longx2 aF[4], bF[2];

    // ---- phase 0: stage full kt s+1 (3 loads); read aF + b(n0,n1); MFMA n0,n1
    stage_A8(Ag, Asn, kn, tid);
    stage_B8(Tg, Bsn, kn, tid);
#pragma unroll
    for (int m = 0; m < 4; ++m)
      aF[m] = frag8(Asb, wm * 64 + m * 16 + lrow, lq);
#pragma unroll
    for (int n = 0; n < 2; ++n)
      bF[n] = frag8(Bsb, wn * 64 + n * 16 + lrow, lq);
    BAR();
    LGKM0();
    __builtin_amdgcn_s_setprio(1);
#pragma unroll
    for (int m = 0; m < 4; ++m)
#pragma unroll
      for (int n = 0; n < 2; ++n) {
        acc[m][n] = __builtin_amdgcn_mfma_f32_16x16x32_fp8_fp8(aF[m].x, bF[n].x, acc[m][n], 0, 0, 0);
        acc[m][n] = __builtin_amdgcn_mfma_f32_16x16x32_fp8_fp8(aF[m].y, bF[n].y, acc[m][n], 0, 0, 0);
      }
    __builtin_amdgcn_s_setprio(0);
    BAR();

    // ---- phase 1: read b(n2,n3); MFMA n2,n3; drain pinned after MFMA
#pragma unroll
    for (int n = 0; n < 2; ++n)
      bF[n] = frag8(Bsb, wn * 64 + (n + 2) * 16 + lrow, lq);
    BAR();
    LGKM0();
    __builtin_amdgcn_s_setprio(1);
#pragma unroll
    for (int m = 0; m < 4; ++m)
#pragma unroll
      for (int n = 0; n < 2; ++n) {
        acc[m][n + 2] = __builtin_amdgcn_mfma_f32_16x16x32_fp8_fp8(aF[m].x, bF[n].x, acc[m][n + 2], 0, 0, 0);
        acc[m][n + 2] = __builtin_amdgcn_mfma_f32_16x16x32_fp8_fp8(aF[m].y, bF[n].y, acc[m][n + 2], 0, 0, 0);
      }
    __builtin_amdgcn_s_setprio(0);
    __builtin_amdgcn_sched_barrier(0);   // keep MFMA above the drain
    VMCNT0();                            // kt s+1 landed; cross-block TLP covers
    BAR();
  }

  VMCNT0();  // drain the wrapped final-iteration stages before LDS goes away

  // Epilogue: per C-row partial sum of exp(sim*20) over this block's 256 cols.
#pragma unroll
  for (int m = 0; m < 4; ++m) {
#pragma unroll
    for (int j2 = 0; j2 < 4; ++j2) {
      float s = __expf(acc[m][0][j2] * INV_TEMP) + __expf(acc[m][1][j2] * INV_TEMP) +
                __expf(acc[m][2][j2] * INV_TEMP) + __expf(acc[m][3][j2] * INV_TEMP);
      s += __shfl_xor(s, 1, 64);
      s += __shfl_xor(s, 2, 64);
      s += __shfl_xor(s, 4, 64);
      s += __shfl_xor(s, 8, 64);
      if (lrow == 0) {
        int grow = tm * BM + wm * 64 + m * 16 + lq * 4 + j2;
        atomicAdd(&sumexp[grow], s);
      }
    }
  }
}

// ---------------------------------------------------------------------------
// Kernel 3: final scalar reduction.
// ---------------------------------------------------------------------------
__global__ __launch_bounds__(256) void finalize_kernel(
    const float* __restrict__ sumexp, const float* __restrict__ pos_score,
    const float* __restrict__ kl, float* __restrict__ out) {
  int tid = threadIdx.x;
  float kls = 0.f, ces = 0.f;
  for (int i = tid; i < NB; i += 256) {
    kls += kl[i];
    ces += logf(sumexp[i]) - pos_score[i] * INV_TEMP;
  }
#pragma unroll
  for (int off = 32; off; off >>= 1) {
    kls += __shfl_xor(kls, off, 64);
    ces += __shfl_xor(ces, off, 64);
  }
  __shared__ float sk[4], se4[4];
  int wid = tid >> 6, lane = tid & 63;
  if (lane == 0) { sk[wid] = kls; se4[wid] = ces; }
  __syncthreads();
  if (tid == 0) {
    float k4 = sk[0] + sk[1] + sk[2] + sk[3];
    float e4 = se4[0] + se4[1] + se4[2] + se4[3];
    out[0] = 0.5f * (k4 / (float)NB) + 1.0f * (e4 / (float)NB);
  }
}

extern "C" void kernel_launch(void* const* d_in, const int* in_sizes, int n_in,
                              void* d_out, int out_size, void* d_ws, size_t ws_size,
                              hipStream_t stream) {
  const float* emb = (const float*)d_in[0];
  const float* scores = (const float*)d_in[1];
  float* out = (float*)d_out;

  char* ws = (char*)d_ws;
  size_t offA = 0;
  size_t offT = offA + (size_t)NB * ND;          // fp8: 1 B/elem
  size_t offSum = offT + (size_t)NTGT * ND;
  size_t offPos = offSum + (size_t)NB * 4;
  size_t offKl = offPos + (size_t)NB * 4;

  unsigned char* A8 = (unsigned char*)(ws + offA);
  unsigned char* T8 = (unsigned char*)(ws + offT);
  float* sumexp = (float*)(ws + offSum);
  float* pos_score = (float*)(ws + offPos);
  float* kl = (float*)(ws + offKl);

  hipMemsetAsync(sumexp, 0, (size_t)NB * 4, stream);
  prep_kernel<<<NB, 256, 0, stream>>>(emb, scores, A8, T8, pos_score, kl);
  gemm_lse_kernel<<<dim3(TM_TILES * TN_TILES), 512, 0, stream>>>(A8, T8, sumexp);
  finalize_kernel<<<1, 256, 0, stream>>>(sumexp, pos_score, kl, out);
}

// Round 11
// 90.851 us; speedup vs baseline: 6.9172x; 1.0781x over previous
//
#include <hip/hip_runtime.h>
#include <hip/hip_bf16.h>
#include <stdint.h>

#define NB 2048
#define NR 10
#define ND 1024
#define NTGT (NB * (NR - 1))   /* 18432 targets */
#define INV_TEMP 20.0f

#define BM 128
#define BN 256
#define BK 64                  /* fp8: 64 B rows in LDS */
#define NKT (ND / BK)          /* 16 K-tiles */
#define TM_TILES (NB / BM)     /* 16 */
#define TN_TILES (NTGT / BN)   /* 72 */

typedef __attribute__((ext_vector_type(4))) float floatx4;
typedef __attribute__((ext_vector_type(2))) long longx2;

#define BAR()    asm volatile("s_barrier" ::: "memory")
#define VMCNT0() asm volatile("s_waitcnt vmcnt(0)" ::: "memory")
#define VMCNT3() asm volatile("s_waitcnt vmcnt(3)" ::: "memory")

__device__ __forceinline__ void async16(const void* g, void* l) {
  __builtin_amdgcn_global_load_lds(
      (const __attribute__((address_space(1))) unsigned int*)g,
      (__attribute__((address_space(3))) unsigned int*)l,
      16, 0, 0);
}

// ---------------------------------------------------------------------------
// Kernel 1 (fused prep): one block per b. Reads the 10 rows of b ONCE:
// computes 10 norms + 9 anchor-dots, writes normalized FP8 (e4m3) A/T rows,
// KL, pos_score. KL/pos_score stay exact fp32.
// ---------------------------------------------------------------------------
__global__ __launch_bounds__(256) void prep_kernel(
    const float* __restrict__ emb, const float* __restrict__ scores,
    unsigned char* __restrict__ A8, unsigned char* __restrict__ T8,
    float* __restrict__ pos_score, float* __restrict__ kl_out) {
  int b = blockIdx.x;
  int tid = threadIdx.x;             // float4 index within a row (256*4 = 1024)
  int wid = tid >> 6, lane = tid & 63;
  const float* base = emb + (size_t)b * NR * ND;

  float4 v[NR];
  float ss[NR], dt[NR - 1];
#pragma unroll
  for (int r = 0; r < NR; ++r) {
    v[r] = reinterpret_cast<const float4*>(base + (size_t)r * ND)[tid];
    ss[r] = v[r].x * v[r].x + v[r].y * v[r].y + v[r].z * v[r].z + v[r].w * v[r].w;
  }
#pragma unroll
  for (int t = 0; t < NR - 1; ++t)
    dt[t] = v[0].x * v[t + 1].x + v[0].y * v[t + 1].y + v[0].z * v[t + 1].z +
            v[0].w * v[t + 1].w;

#pragma unroll
  for (int off = 32; off; off >>= 1) {
#pragma unroll
    for (int r = 0; r < NR; ++r) ss[r] += __shfl_xor(ss[r], off, 64);
#pragma unroll
    for (int t = 0; t < NR - 1; ++t) dt[t] += __shfl_xor(dt[t], off, 64);
  }
  __shared__ float red[4][2 * NR - 1];
  if (lane == 0) {
#pragma unroll
    for (int r = 0; r < NR; ++r) red[wid][r] = ss[r];
#pragma unroll
    for (int t = 0; t < NR - 1; ++t) red[wid][NR + t] = dt[t];
  }
  __syncthreads();

  float inv[NR];
#pragma unroll
  for (int r = 0; r < NR; ++r) {
    float s = red[0][r] + red[1][r] + red[2][r] + red[3][r];
    inv[r] = 1.0f / fmaxf(sqrtf(s), 1e-12f);
  }

  // write normalized fp8 rows (4 bytes/thread/row)
#pragma unroll
  for (int r = 0; r < NR; ++r) {
    unsigned char* dst;
    if (r == 0)      dst = A8 + (size_t)b * ND;
    else if (r == 1) dst = T8 + (size_t)b * ND;
    else             dst = T8 + (size_t)(NB + b * 8 + (r - 2)) * ND;
    int p = 0;
    p = __builtin_amdgcn_cvt_pk_fp8_f32(v[r].x * inv[r], v[r].y * inv[r], p, false);
    p = __builtin_amdgcn_cvt_pk_fp8_f32(v[r].z * inv[r], v[r].w * inv[r], p, true);
    reinterpret_cast<int*>(dst)[tid] = p;
  }

  if (tid == 0) {
    float rs[NR - 1];
#pragma unroll
    for (int t = 0; t < NR - 1; ++t) {
      float d = red[0][NR + t] + red[1][NR + t] + red[2][NR + t] + red[3][NR + t];
      rs[t] = d * inv[0] * inv[t + 1];
    }
    float sc[NR - 1], ms = -1e30f;
#pragma unroll
    for (int k = 0; k < NR - 1; ++k) { sc[k] = scores[b * (NR - 1) + k]; ms = fmaxf(ms, sc[k]); }
    float se = 0.f;
#pragma unroll
    for (int k = 0; k < NR - 1; ++k) { sc[k] = expf(sc[k] - ms); se += sc[k]; }
    float mr = -1e30f;
#pragma unroll
    for (int k = 0; k < NR - 1; ++k) mr = fmaxf(mr, rs[k]);
    float sr = 0.f;
#pragma unroll
    for (int k = 0; k < NR - 1; ++k) sr += expf(rs[k] - mr);
    float lz = logf(sr) + mr;
    float kl = 0.f;
#pragma unroll
    for (int k = 0; k < NR - 1; ++k) {
      float ce = sc[k] / se;
      kl += ce * logf(ce) - ce * (rs[k] - lz);
    }
    kl_out[b] = kl / (float)(NR - 1);
    pos_score[b] = rs[0];
  }
}

// ---------------------------------------------------------------------------
// Kernel 2: 128x256x64 FP8 (e4m3) GEMM + sum-exp epilogue, 2 blocks/CU.
// TRIPLE-buffered LDS (72 KiB), counted vmcnt(3), ONE barrier per K-iter.
// iter s: stage kt s+2 -> buf(s+2)%3; read kt s from buf s%3; 32 MFMA;
// vmcnt(3) (= kt s+1 landed, issued a full iter ago); s_barrier.
// Safety: reads of a buffer retire (compiler lgkmcnt before consuming MFMA)
// before that wave's barrier; the buffer is only rewritten after that barrier.
// Writes are issuer-confirmed by each wave's own vmcnt(3) one iter later,
// before the barrier that releases readers.
// ---------------------------------------------------------------------------

// Stage A K-slice: 128 rows x 64 B = 8 KB, 1 load/thread.
__device__ __forceinline__ void stage_A8(const unsigned char* __restrict__ gtile,
                                         unsigned char* lds, int k0, int tid) {
  int lrow = tid >> 2;                 // 0..127
  int u = (tid & 3) ^ ((lrow >> 1) & 3);
  const unsigned char* src = gtile + (size_t)lrow * ND + k0 + u * 16;
  unsigned char* dst = lds + (tid & ~63) * 16;  // wave-uniform base, +lane*16B
  async16(src, dst);
}

// Stage B K-slice: 256 rows x 64 B = 16 KB, 2 loads/thread.
__device__ __forceinline__ void stage_B8(const unsigned char* __restrict__ gtile,
                                         unsigned char* lds, int k0, int tid) {
#pragma unroll
  for (int r = 0; r < 2; ++r) {
    int slot = r * 512 + tid;          // 0..1023
    int lrow = slot >> 2;              // 0..255
    int u = (slot & 3) ^ ((lrow >> 1) & 3);
    const unsigned char* src = gtile + (size_t)lrow * ND + k0 + u * 16;
    unsigned char* dst = lds + (r * 512 + (tid & ~63)) * 16;
    async16(src, dst);
  }
}

// Swizzled fragment-pair read: one b128; .x = kk0 (bytes lq*16..+7),
// .y = kk1 (bytes lq*16+8..+15). k-permutation invariance: both A and B use
// the same physical-k relabeling, so the dot product is unchanged.
__device__ __forceinline__ longx2 frag8(const unsigned char* lds, int row, int lq) {
  int byte = row * 64 + ((lq * 16) ^ (((row >> 1) & 3) << 4));
  return *reinterpret_cast<const longx2*>(lds + byte);
}

__global__ __launch_bounds__(512, 4) void gemm_lse_kernel(
    const unsigned char* __restrict__ A, const unsigned char* __restrict__ T,
    float* __restrict__ sumexp) {
  // 72 KiB: 3 x [As 8K][Bs 16K]
  __shared__ unsigned char smem[3 * (BM + BN) * BK];

  int bid = blockIdx.x;             // 1152 = 8 * 144
  int xcd = bid & 7;
  int j = bid >> 3;                 // 0..143
  int tn = xcd * 9 + (j >> 4);      // 9 B-panels per XCD
  int tm = j & 15;

  int tid = threadIdx.x;
  int wid = tid >> 6, lane = tid & 63;
  int wm = wid >> 2, wn = wid & 3;  // 2 x 4 waves; wave tile 64 x 64
  int lrow = lane & 15, lq = lane >> 4;

  const unsigned char* Ag = A + (size_t)tm * BM * ND;
  const unsigned char* Tg = T + (size_t)tn * BN * ND;

  floatx4 acc[4][4] = {};

  unsigned char* bufA0 = smem;
  unsigned char* bufB0 = smem + BM * BK;
  unsigned char* bufA1 = smem + (BM + BN) * BK;
  unsigned char* bufB1 = bufA1 + BM * BK;
  unsigned char* bufA2 = smem + 2 * (BM + BN) * BK;
  unsigned char* bufB2 = bufA2 + BM * BK;

  // Prologue: stage kt0 -> buf0, kt1 -> buf1; wait kt0 (3 outstanding = kt1).
  stage_A8(Ag, bufA0, 0, tid);
  stage_B8(Tg, bufB0, 0, tid);
  stage_A8(Ag, bufA1, BK, tid);
  stage_B8(Tg, bufB1, BK, tid);
  VMCNT3();
  BAR();

  const unsigned char* Acur = bufA0;  const unsigned char* Bcur = bufB0;
  unsigned char* Anxt = bufA1;        unsigned char* Bnxt = bufB1;   // kt s+1
  unsigned char* Afar = bufA2;        unsigned char* Bfar = bufB2;   // kt s+2 target

  for (int s = 0; s < NKT; ++s) {
    const int kn = ((s + 2) & (NKT - 1)) * BK;  // wrap: last 2 iters stage into
                                                // dead buffers (harmless)
    // stage kt s+2 (3 loads/thread, issued first for max slack)
    stage_A8(Ag, Afar, kn, tid);
    stage_B8(Tg, Bfar, kn, tid);

    longx2 aF[4], bF[4];
#pragma unroll
    for (int m = 0; m < 4; ++m)
      aF[m] = frag8(Acur, wm * 64 + m * 16 + lrow, lq);
#pragma unroll
    for (int n = 0; n < 4; ++n)
      bF[n] = frag8(Bcur, wn * 64 + n * 16 + lrow, lq);

    __builtin_amdgcn_s_setprio(1);
#pragma unroll
    for (int m = 0; m < 4; ++m)
#pragma unroll
      for (int n = 0; n < 4; ++n) {
        acc[m][n] = __builtin_amdgcn_mfma_f32_16x16x32_fp8_fp8(aF[m].x, bF[n].x, acc[m][n], 0, 0, 0);
        acc[m][n] = __builtin_amdgcn_mfma_f32_16x16x32_fp8_fp8(aF[m].y, bF[n].y, acc[m][n], 0, 0, 0);
      }
    __builtin_amdgcn_s_setprio(0);

    VMCNT3();   // kt s+1 fully landed (its 3 loads issued one full iter ago)
    BAR();

    // rotate buffers
    unsigned char* ta = (unsigned char*)Acur;  unsigned char* tb = (unsigned char*)Bcur;
    Acur = Anxt;  Bcur = Bnxt;
    Anxt = Afar;  Bnxt = Bfar;
    Afar = ta;    Bfar = tb;
  }

  VMCNT0();  // drain wrapped final stages before LDS is released

  // Epilogue: per C-row partial sum of exp(sim*20) over this block's 256 cols.
#pragma unroll
  for (int m = 0; m < 4; ++m) {
#pragma unroll
    for (int j2 = 0; j2 < 4; ++j2) {
      float s = __expf(acc[m][0][j2] * INV_TEMP) + __expf(acc[m][1][j2] * INV_TEMP) +
                __expf(acc[m][2][j2] * INV_TEMP) + __expf(acc[m][3][j2] * INV_TEMP);
      s += __shfl_xor(s, 1, 64);
      s += __shfl_xor(s, 2, 64);
      s += __shfl_xor(s, 4, 64);
      s += __shfl_xor(s, 8, 64);
      if (lrow == 0) {
        int grow = tm * BM + wm * 64 + m * 16 + lq * 4 + j2;
        atomicAdd(&sumexp[grow], s);
      }
    }
  }
}

// ---------------------------------------------------------------------------
// Kernel 3: final scalar reduction.
// ---------------------------------------------------------------------------
__global__ __launch_bounds__(256) void finalize_kernel(
    const float* __restrict__ sumexp, const float* __restrict__ pos_score,
    const float* __restrict__ kl, float* __restrict__ out) {
  int tid = threadIdx.x;
  float kls = 0.f, ces = 0.f;
  for (int i = tid; i < NB; i += 256) {
    kls += kl[i];
    ces += logf(sumexp[i]) - pos_score[i] * INV_TEMP;
  }
#pragma unroll
  for (int off = 32; off; off >>= 1) {
    kls += __shfl_xor(kls, off, 64);
    ces += __shfl_xor(ces, off, 64);
  }
  __shared__ float sk[4], se4[4];
  int wid = tid >> 6, lane = tid & 63;
  if (lane == 0) { sk[wid] = kls; se4[wid] = ces; }
  __syncthreads();
  if (tid == 0) {
    float k4 = sk[0] + sk[1] + sk[2] + sk[3];
    float e4 = se4[0] + se4[1] + se4[2] + se4[3];
    out[0] = 0.5f * (k4 / (float)NB) + 1.0f * (e4 / (float)NB);
  }
}

extern "C" void kernel_launch(void* const* d_in, const int* in_sizes, int n_in,
                              void* d_out, int out_size, void* d_ws, size_t ws_size,
                              hipStream_t stream) {
  const float* emb = (const float*)d_in[0];
  const float* scores = (const float*)d_in[1];
  float* out = (float*)d_out;

  char* ws = (char*)d_ws;
  size_t offA = 0;
  size_t offT = offA + (size_t)NB * ND;          // fp8: 1 B/elem
  size_t offSum = offT + (size_t)NTGT * ND;
  size_t offPos = offSum + (size_t)NB * 4;
  size_t offKl = offPos + (size_t)NB * 4;

  unsigned char* A8 = (unsigned char*)(ws + offA);
  unsigned char* T8 = (unsigned char*)(ws + offT);
  float* sumexp = (float*)(ws + offSum);
  float* pos_score = (float*)(ws + offPos);
  float* kl = (float*)(ws + offKl);

  hipMemsetAsync(sumexp, 0, (size_t)NB * 4, stream);
  prep_kernel<<<NB, 256, 0, stream>>>(emb, scores, A8, T8, pos_score, kl);
  gemm_lse_kernel<<<dim3(TM_TILES * TN_TILES), 512, 0, stream>>>(A8, T8, sumexp);
  finalize_kernel<<<1, 256, 0, stream>>>(sumexp, pos_score, kl, out);
}